// Round 3
// baseline (1451.845 us; speedup 1.0000x reference)
//
#include <hip/hip_runtime.h>
#include <hip/hip_fp16.h>
#include <math.h>

// dst-CSR built with ZERO N-wide passes (unchanged):
//   bucket_hist_k / bucket_scan_k / binsort_k / fill2_k.
// gemm_k: no W staging (L1-resident), 64-row x tile; epilogue writes
//   SLICE-MAJOR fp16 state (4 slices x 16 features, 32 B/row-slice).
// prop_k (this round): feature-sliced, XCD-pinned propagation.
//   State working set per slice = 3.2 MB -> resident in the 4 MB per-XCD L2.
//   slice = (blockIdx%8)>>1 pins each slice to one XCD pair (HW round-robins
//   blockIdx across the 8 XCDs). Wave = 1 (row, slice): 4 lanes x 8 B per row,
//   16 edges per dwordx2 gather instruction; fdot2 f32 accumulate.

#define BSH 8        // 256 dsts per bucket (CSR build)
#define NSL 4        // feature slices
// per-slice row = 16 fp16 = 32 B

typedef _Float16 h2_t __attribute__((ext_vector_type(2)));
union U8 { uint2 u; h2_t h[2]; };

// ---------------- small utils ----------------

__global__ void zero_i32(int* __restrict__ p, int n) {
    int i = blockIdx.x * blockDim.x + threadIdx.x;
    if (i < n) p[i] = 0;
}

// zero dummy row N of each slice of the three gather buffers
__global__ void zero_dummy(__half2* __restrict__ b0, __half2* __restrict__ b1,
                           __half2* __restrict__ b2, int N) {
    int t = threadIdx.x;
    if (t >= 96) return;              // 3 buffers x 4 slices x 8 half2
    __half2* b = (t < 32) ? b0 : (t < 64) ? b1 : b2;
    int r = t & 31;
    int s = r >> 3, h = r & 7;
    b[((size_t)s * (N + 1) + N) * 8 + h] = __floats2half2_rn(0.f, 0.f);
}

// ---------------- bucket histogram (LDS-aggregated) ----------------

__global__ void __launch_bounds__(256) bucket_hist_k(const int* __restrict__ dst, int E,
                                                     int* __restrict__ bktcnt) {
    __shared__ int hist[400];
    int t = threadIdx.x;
    for (int i = t; i < 400; i += 256) hist[i] = 0;
    __syncthreads();
    int e0 = blockIdx.x * 4096 + t;
#pragma unroll
    for (int i = 0; i < 16; ++i) {
        int e = e0 + i * 256;
        if (e < E) atomicAdd(&hist[dst[e] >> BSH], 1);
    }
    __syncthreads();
    for (int b = t; b < 400; b += 256) {
        int c = hist[b];
        if (c > 0) atomicAdd(&bktcnt[b], c);
    }
}

// ---------------- 1-block scan of bucket totals -> bases + padded cursors ----------------

__global__ void bucket_scan_k(const int* __restrict__ bktcnt, int nb, int E,
                              int* __restrict__ bktbase, int* __restrict__ bktcur) {
    __shared__ int s[256];
    int t = threadIdx.x;
    int C = (nb + 255) / 256;            // <= 8
    int b0 = t * C;
    int loc[8]; int sum = 0;
    for (int i = 0; i < C; ++i) {
        int v = (b0 + i < nb) ? bktcnt[b0 + i] : 0;
        loc[i] = sum; sum += v;
    }
    s[t] = sum; __syncthreads();
    for (int off = 1; off < 256; off <<= 1) {
        int v = (t >= off) ? s[t - off] : 0;
        __syncthreads();
        s[t] += v;
        __syncthreads();
    }
    int excl = s[t] - sum;
    for (int i = 0; i < C; ++i)
        if (b0 + i < nb) {
            int e0 = excl + loc[i];
            bktbase[b0 + i] = e0;
            bktcur[(b0 + i) * 16] = e0;  // 64B-padded cursor
        }
    if (t == 0) bktbase[nb] = E;
}

// ---------------- bin edges by bucket (dst>>8), contiguous runs ----------------

__global__ void __launch_bounds__(256) binsort_k(const int* __restrict__ src,
                                                 const int* __restrict__ dst, int E,
                                                 int* __restrict__ bktcur,  // padded x16
                                                 unsigned* __restrict__ binned) {
    __shared__ int hist[400], gbase[400], lcur[400];
    int t = threadIdx.x;
    for (int i = t; i < 400; i += 256) { hist[i] = 0; lcur[i] = 0; }
    __syncthreads();

    int e0 = blockIdx.x * 4096 + t;
    unsigned rec[16]; int bk[16];
#pragma unroll
    for (int i = 0; i < 16; ++i) {
        int e = e0 + i * 256;
        if (e < E) {
            int s = src[e], d = dst[e];
            bk[i]  = d >> BSH;
            rec[i] = ((unsigned)s << BSH) | (unsigned)(d & 255);
            atomicAdd(&hist[bk[i]], 1);
        } else bk[i] = -1;
    }
    __syncthreads();
    for (int b = t; b < 400; b += 256) {
        int c = hist[b];
        if (c > 0) gbase[b] = atomicAdd(&bktcur[b * 16], c);
    }
    __syncthreads();
#pragma unroll
    for (int i = 0; i < 16; ++i) {
        if (bk[i] >= 0) {
            int loc = atomicAdd(&lcur[bk[i]], 1);
            binned[gbase[bk[i]] + loc] = rec[i];
        }
    }
}

// ---------------- per-bucket: degrees + rowptr + dinv + col scatter ----------------

__global__ void __launch_bounds__(256) fill2_k(const unsigned* __restrict__ binned,
                                               const int* __restrict__ bktbase,
                                               int N, int E, int NB,
                                               int* __restrict__ rowptr,
                                               float* __restrict__ dinv,
                                               int* __restrict__ col) {
    __shared__ int cnt[256], excl[256], lcur[256];
    int b = blockIdx.x, t = threadIdx.x;
    int beg = bktbase[b], end = bktbase[b + 1];
    cnt[t] = 0;
    __syncthreads();
    for (int i = beg + t; i < end; i += 256)
        atomicAdd(&cnt[binned[i] & 255u], 1);
    __syncthreads();
    int v = cnt[t];
    excl[t] = v;
    __syncthreads();
    for (int off = 1; off < 256; off <<= 1) {
        int u = (t >= off) ? excl[t - off] : 0;
        __syncthreads();
        excl[t] += u;
        __syncthreads();
    }
    int ex = excl[t] - v;                // exclusive prefix within bucket
    lcur[t] = ex;
    int d = (b << BSH) + t;
    if (d < N) {
        rowptr[d] = beg + ex;            // coalesced
        dinv[d] = rsqrtf((float)(v + 1));  // +1 self-loop
    }
    if (b == NB - 1 && t == 0) rowptr[N] = E;
    __syncthreads();
    for (int i = beg + t; i < end; i += 256) {
        unsigned r = binned[i];
        int loc = atomicAdd(&lcur[r & 255u], 1);
        col[beg + loc] = (int)(r >> BSH);   // scatter inside this bucket's segment
    }
}

// ---------------- g0 = x @ W : 64-row tile, W from global (L1-resident) ----------------
// Slice-major epilogue: feature j lives in slice j/16 at offset j%16.
// g0t[slice][n] = g0 (teleport, unscaled); g0h[slice][n] = dinv[n]*g0 (state).

__global__ void __launch_bounds__(256) gemm_k(const float* __restrict__ x,
                                              const float* __restrict__ W,
                                              const float* __restrict__ dinv,
                                              __half2* __restrict__ g0t,
                                              __half2* __restrict__ g0h, int N) {
    __shared__ float xs[64 * 133];        // ~34 KB -> 4 blocks/CU
    int t = threadIdx.x;
    int n0 = blockIdx.x * 64;
    for (int f = t; f < 64 * 32; f += 256) {
        int r = f >> 5, c4 = f & 31;
        int n = n0 + r;
        float4 v = (n < N) ? ((const float4*)x)[(size_t)n * 32 + c4]
                           : make_float4(0.f, 0.f, 0.f, 0.f);
        float* dp = &xs[r * 133 + c4 * 4];
        dp[0] = v.x; dp[1] = v.y; dp[2] = v.z; dp[3] = v.w;
    }
    __syncthreads();
    int tr = t & 15, tc = t >> 4;
    int r0 = tc * 4;
    const float4* W4 = (const float4*)W;  // 32 KB total -> L1-resident
    float acc[4][4] = {};
#pragma unroll 8
    for (int k = 0; k < 128; ++k) {
        float4 wv = W4[k * 16 + tr];      // 256 B/k, broadcast across tc, L1 hit
#pragma unroll
        for (int i = 0; i < 4; ++i) {
            float xv = xs[(r0 + i) * 133 + k];
            acc[i][0] += xv * wv.x; acc[i][1] += xv * wv.y;
            acc[i][2] += xv * wv.z; acc[i][3] += xv * wv.w;
        }
    }
    int slice = tr >> 2;                  // j0 = tr*4 -> slice j0/16
    int o = (tr & 3) * 2;                 // half2 offset within the 32-B slice row
#pragma unroll
    for (int i = 0; i < 4; ++i) {
        int n = n0 + r0 + i;
        if (n < N) {
            float dn = dinv[n];
            size_t rb = ((size_t)slice * (N + 1) + n) * 8;
            g0t[rb + o]     = __floats2half2_rn(acc[i][0], acc[i][1]);
            g0t[rb + o + 1] = __floats2half2_rn(acc[i][2], acc[i][3]);
            g0h[rb + o]     = __floats2half2_rn(acc[i][0] * dn, acc[i][1] * dn);
            g0h[rb + o + 1] = __floats2half2_rn(acc[i][2] * dn, acc[i][3] * dn);
        }
    }
}

// ---------------- propagation: feature-sliced, XCD-pinned ----------------
// Grid = pairs*8 blocks; xcd = bid&7; slice = xcd>>1 (one slice per XCD pair,
// relies on HW round-robin blockIdx->XCD). Block = 4 waves = 4 rows of that
// slice. Wave lanes: sub = lane>>2 in [0,16) = edge slot, q = lane&3 = 8-B
// segment of the 32-B slice row. One dwordx2 gather instr covers 16 edges.

__global__ void __launch_bounds__(256) prop_k(const __half2* __restrict__ gin,
                                              const __half2* __restrict__ g0t,
                                              __half2* __restrict__ gout,
                                              float* __restrict__ outf,
                                              const int* __restrict__ rowptr,
                                              const int* __restrict__ cols,
                                              const float* __restrict__ dinv,
                                              const float* __restrict__ bias,
                                              int N, int nseq, int final_step) {
    int bid = blockIdx.x;
    int xcd = bid & 7;
    int slice = xcd >> 1;
    int seq = (bid >> 3) * 2 + (xcd & 1);
    if (seq >= nseq) return;
    int gw = seq * 4 + (threadIdx.x >> 6);
    if (gw >= N) return;

    int lane = threadIdx.x & 63;
    int sub = lane >> 2;      // edge slot 0..15
    int q   = lane & 3;       // 8-B segment 0..3
    int l32 = lane & 31;
    int qo  = q * 8;

    size_t srow = (size_t)slice * (N + 1);
    const char* gb = (const char*)gin + srow * 32;

    int beg = rowptr[gw], end = rowptr[gw + 1];
    int deg = end - beg;
    float di = dinv[gw];

    // self + teleport segments (whole wave reads same 32-B row: 1 line each)
    U8 gi; gi.u = *(const uint2*)(gb + (size_t)gw * 32 + qo);
    U8 g0; g0.u = *(const uint2*)((const char*)g0t + (srow + gw) * 32 + qo);

    const h2_t SEL_LO = {(_Float16)1.f, (_Float16)0.f};
    const h2_t SEL_HI = {(_Float16)0.f, (_Float16)1.f};

    float a[4] = {};   // 4 f32 accumulators = this lane's 4 feature cols

    int full = deg & ~31;
    for (int base = 0; base < full; base += 32) {
        int ci = cols[beg + base + l32];   // 32 cols, one load, all valid
#pragma unroll
        for (int i = 0; i < 2; ++i) {
            int c = __shfl(ci, i * 16 + sub, 64);
            U8 v; v.u = *(const uint2*)(gb + (size_t)c * 32 + qo);
            a[0] = __builtin_amdgcn_fdot2(v.h[0], SEL_LO, a[0], false);
            a[1] = __builtin_amdgcn_fdot2(v.h[0], SEL_HI, a[1], false);
            a[2] = __builtin_amdgcn_fdot2(v.h[1], SEL_LO, a[2], false);
            a[3] = __builtin_amdgcn_fdot2(v.h[1], SEL_HI, a[3], false);
        }
    }
    int m = deg - full;                    // 0..31 tail edges
    if (m > 0) {
        int ci = cols[beg + full + (l32 < m ? l32 : 0)];
#pragma unroll 2
        for (int i = 0; i * 16 < m; ++i) {
            int e = i * 16 + sub;
            int c = __shfl(ci, e, 64);
            if (e >= m) c = N;             // per-slice dummy zero row
            U8 v; v.u = *(const uint2*)(gb + (size_t)c * 32 + qo);
            a[0] = __builtin_amdgcn_fdot2(v.h[0], SEL_LO, a[0], false);
            a[1] = __builtin_amdgcn_fdot2(v.h[0], SEL_HI, a[1], false);
            a[2] = __builtin_amdgcn_fdot2(v.h[1], SEL_LO, a[2], false);
            a[3] = __builtin_amdgcn_fdot2(v.h[1], SEL_HI, a[3], false);
        }
    }

    // reduce across the 16 edge slots (lanes with equal q)
#pragma unroll
    for (int off = 4; off < 64; off <<= 1) {
#pragma unroll
        for (int u = 0; u < 4; ++u) a[u] += __shfl_xor(a[u], off, 64);
    }

    if (sub == 0) {   // 4 lanes, each owns features [slice*16+4q, +4)
        float2 gi0 = __half22float2(*(__half2*)&gi.h[0]);
        float2 gi1 = __half22float2(*(__half2*)&gi.h[1]);
        float2 g00 = __half22float2(*(__half2*)&g0.h[0]);
        float2 g01 = __half22float2(*(__half2*)&g0.h[1]);
        float r0 = 0.9f * di * (a[0] + gi0.x) + 0.1f * g00.x;
        float r1 = 0.9f * di * (a[1] + gi0.y) + 0.1f * g00.y;
        float r2 = 0.9f * di * (a[2] + gi1.x) + 0.1f * g01.x;
        float r3 = 0.9f * di * (a[3] + gi1.y) + 0.1f * g01.y;
        if (final_step) {
            float4 bv = ((const float4*)bias)[slice * 4 + q];
            float4* op = (float4*)(outf + (size_t)gw * 64 + slice * 16 + q * 4);
            *op = make_float4(r0 + bv.x, r1 + bv.y, r2 + bv.z, r3 + bv.w);
        } else {
            U8 o;
            o.h[0] = (h2_t)__floats2half2_rn(di * r0, di * r1).data;
            o.h[1] = (h2_t)__floats2half2_rn(di * r2, di * r3).data;
            __half2 o0 = __floats2half2_rn(di * r0, di * r1);
            __half2 o1 = __floats2half2_rn(di * r2, di * r3);
            __half2* gp = (__half2*)((char*)gout + (srow + gw) * 32 + qo);
            gp[0] = o0; gp[1] = o1;
        }
    }
}

// ---------------- launch ----------------

extern "C" void kernel_launch(void* const* d_in, const int* in_sizes, int n_in,
                              void* d_out, int out_size, void* d_ws, size_t ws_size,
                              hipStream_t stream) {
    const float* x  = (const float*)d_in[0];
    const int*   ei = (const int*)d_in[1];
    const float* W  = (const float*)d_in[2];
    const float* b  = (const float*)d_in[3];
    float* out = (float*)d_out;

    const int N = in_sizes[0] / 128;
    const int E = in_sizes[1] / 2;
    const int* src = ei;
    const int* dst = ei + E;
    const int NB = (N + 255) >> BSH;     // buckets of 256 dsts

    char* w = (char*)d_ws;
    size_t off = 0;
    auto alloc = [&](size_t bytes) -> void* {
        void* p = w + off;
        off += (bytes + 255) & ~(size_t)255;
        return p;
    };
    // slice-major fp16 state: NSL slices x (N+1) rows x 32 B
    const size_t fp16buf = (size_t)NSL * (N + 1) * 32;
    __half2*  g0h    = (__half2*) alloc(fp16buf);   // dinv-scaled initial state
    __half2*  bufA   = (__half2*) alloc(fp16buf);
    __half2*  bufB   = (__half2*) alloc(fp16buf);
    __half2*  g0t    = (__half2*) alloc(fp16buf);   // teleport term (unscaled)
    int*      cols   = (int*)     alloc((size_t)E * 4);
    unsigned* binned = (unsigned*)alloc((size_t)E * 4);
    int*      rowptr = (int*)     alloc((size_t)(N + 1) * 4);
    int*      bktcnt = (int*)     alloc((size_t)NB * 4);
    int*      bktbase= (int*)     alloc((size_t)(NB + 1) * 4);
    int*      bktcur = (int*)     alloc((size_t)NB * 16 * 4);    // 64B-padded
    float*    dinvv  = (float*)   alloc((size_t)N * 4);

    const int nblkB = (E + 4095) / 4096;

    // ---- build dst-CSR: bucket hist -> scan -> binsort -> per-bucket fill ----
    zero_i32<<<(NB + 255) / 256, 256, 0, stream>>>(bktcnt, NB);
    bucket_hist_k<<<nblkB, 256, 0, stream>>>(dst, E, bktcnt);
    zero_dummy<<<1, 96, 0, stream>>>(g0h, bufA, bufB, N);
    bucket_scan_k<<<1, 256, 0, stream>>>(bktcnt, NB, E, bktbase, bktcur);
    binsort_k<<<nblkB, 256, 0, stream>>>(src, dst, E, bktcur, binned);
    fill2_k<<<NB, 256, 0, stream>>>(binned, bktbase, N, E, NB, rowptr, dinvv, cols);

    // g0 = x @ W (propagation commutes with the linear head)
    gemm_k<<<(N + 63) / 64, 256, 0, stream>>>(x, W, dinvv, g0t, g0h, N);

    // K = 10 APPNP steps, fp16 ping-pong; last step writes fp32 d_out (+bias)
    const int nseq  = (N + 3) / 4;            // 4 rows per block
    const int pairs = (nseq + 1) / 2;         // 2 blocks per slice-pair step
    const int grid  = pairs * 8;              // 8 XCD lanes (4 slices x 2)
    const __half2* gin = g0h;
    __half2* pp[2] = {bufA, bufB};
    for (int k = 0; k < 10; ++k) {
        const bool fin = (k == 9);
        __half2* gout = pp[k & 1];
        prop_k<<<grid, 256, 0, stream>>>(gin, g0t, gout, out, rowptr, cols,
                                         dinvv, b, N, nseq, fin ? 1 : 0);
        gin = gout;
    }
}

// Round 4
// 1302.329 us; speedup vs baseline: 1.1148x; 1.1148x over previous
//
#include <hip/hip_runtime.h>
#include <hip/hip_fp16.h>
#include <math.h>

// dst-CSR built with ZERO N-wide passes (unchanged):
//   bucket_hist_k / bucket_scan_k / binsort_k / fill2_k.
// gemm_k: no W staging (L1-resident), 64-row x tile; slice-major fp16 epilogue.
// prop_k (r4): feature-sliced (4 x 32 B, per-slice 3.2 MB -> L2-resident via
//   blockIdx&7 XCD pinning, proven r3: FETCH 168->75 MB) with r2-level
//   instruction efficiency:
//     - wave = 4 rows x 8 edge slots x 2 q-lanes -> 32 edge-gathers/dwordx4
//     - per-lane direct cols load (no shfl distribution)
//     - loop to 4-row max degree; padded lanes hit L1-hot dummy row
//     - non-temporal cols loads (don't evict the resident state slice)
//     - 3-round butterfly reduce, amortized over 4 rows

#define BSH 8        // 256 dsts per bucket (CSR build)
#define NSL 4        // feature slices; per-slice row = 16 fp16 = 32 B

typedef _Float16 h2_t __attribute__((ext_vector_type(2)));
union U16 { uint4 u; h2_t h[4]; };

// ---------------- small utils ----------------

__global__ void zero_i32(int* __restrict__ p, int n) {
    int i = blockIdx.x * blockDim.x + threadIdx.x;
    if (i < n) p[i] = 0;
}

// zero dummy row N of each slice of the three gather buffers
__global__ void zero_dummy(__half2* __restrict__ b0, __half2* __restrict__ b1,
                           __half2* __restrict__ b2, int N) {
    int t = threadIdx.x;
    if (t >= 96) return;              // 3 buffers x 4 slices x 8 half2
    __half2* b = (t < 32) ? b0 : (t < 64) ? b1 : b2;
    int r = t & 31;
    int s = r >> 3, h = r & 7;
    b[((size_t)s * (N + 1) + N) * 8 + h] = __floats2half2_rn(0.f, 0.f);
}

// ---------------- bucket histogram (LDS-aggregated) ----------------

__global__ void __launch_bounds__(256) bucket_hist_k(const int* __restrict__ dst, int E,
                                                     int* __restrict__ bktcnt) {
    __shared__ int hist[400];
    int t = threadIdx.x;
    for (int i = t; i < 400; i += 256) hist[i] = 0;
    __syncthreads();
    int e0 = blockIdx.x * 4096 + t;
#pragma unroll
    for (int i = 0; i < 16; ++i) {
        int e = e0 + i * 256;
        if (e < E) atomicAdd(&hist[dst[e] >> BSH], 1);
    }
    __syncthreads();
    for (int b = t; b < 400; b += 256) {
        int c = hist[b];
        if (c > 0) atomicAdd(&bktcnt[b], c);
    }
}

// ---------------- 1-block scan of bucket totals -> bases + padded cursors ----------------

__global__ void bucket_scan_k(const int* __restrict__ bktcnt, int nb, int E,
                              int* __restrict__ bktbase, int* __restrict__ bktcur) {
    __shared__ int s[256];
    int t = threadIdx.x;
    int C = (nb + 255) / 256;            // <= 8
    int b0 = t * C;
    int loc[8]; int sum = 0;
    for (int i = 0; i < C; ++i) {
        int v = (b0 + i < nb) ? bktcnt[b0 + i] : 0;
        loc[i] = sum; sum += v;
    }
    s[t] = sum; __syncthreads();
    for (int off = 1; off < 256; off <<= 1) {
        int v = (t >= off) ? s[t - off] : 0;
        __syncthreads();
        s[t] += v;
        __syncthreads();
    }
    int excl = s[t] - sum;
    for (int i = 0; i < C; ++i)
        if (b0 + i < nb) {
            int e0 = excl + loc[i];
            bktbase[b0 + i] = e0;
            bktcur[(b0 + i) * 16] = e0;  // 64B-padded cursor
        }
    if (t == 0) bktbase[nb] = E;
}

// ---------------- bin edges by bucket (dst>>8), contiguous runs ----------------

__global__ void __launch_bounds__(256) binsort_k(const int* __restrict__ src,
                                                 const int* __restrict__ dst, int E,
                                                 int* __restrict__ bktcur,  // padded x16
                                                 unsigned* __restrict__ binned) {
    __shared__ int hist[400], gbase[400], lcur[400];
    int t = threadIdx.x;
    for (int i = t; i < 400; i += 256) { hist[i] = 0; lcur[i] = 0; }
    __syncthreads();

    int e0 = blockIdx.x * 4096 + t;
    unsigned rec[16]; int bk[16];
#pragma unroll
    for (int i = 0; i < 16; ++i) {
        int e = e0 + i * 256;
        if (e < E) {
            int s = src[e], d = dst[e];
            bk[i]  = d >> BSH;
            rec[i] = ((unsigned)s << BSH) | (unsigned)(d & 255);
            atomicAdd(&hist[bk[i]], 1);
        } else bk[i] = -1;
    }
    __syncthreads();
    for (int b = t; b < 400; b += 256) {
        int c = hist[b];
        if (c > 0) gbase[b] = atomicAdd(&bktcur[b * 16], c);
    }
    __syncthreads();
#pragma unroll
    for (int i = 0; i < 16; ++i) {
        if (bk[i] >= 0) {
            int loc = atomicAdd(&lcur[bk[i]], 1);
            binned[gbase[bk[i]] + loc] = rec[i];
        }
    }
}

// ---------------- per-bucket: degrees + rowptr + dinv + col scatter ----------------

__global__ void __launch_bounds__(256) fill2_k(const unsigned* __restrict__ binned,
                                               const int* __restrict__ bktbase,
                                               int N, int E, int NB,
                                               int* __restrict__ rowptr,
                                               float* __restrict__ dinv,
                                               int* __restrict__ col) {
    __shared__ int cnt[256], excl[256], lcur[256];
    int b = blockIdx.x, t = threadIdx.x;
    int beg = bktbase[b], end = bktbase[b + 1];
    cnt[t] = 0;
    __syncthreads();
    for (int i = beg + t; i < end; i += 256)
        atomicAdd(&cnt[binned[i] & 255u], 1);
    __syncthreads();
    int v = cnt[t];
    excl[t] = v;
    __syncthreads();
    for (int off = 1; off < 256; off <<= 1) {
        int u = (t >= off) ? excl[t - off] : 0;
        __syncthreads();
        excl[t] += u;
        __syncthreads();
    }
    int ex = excl[t] - v;                // exclusive prefix within bucket
    lcur[t] = ex;
    int d = (b << BSH) + t;
    if (d < N) {
        rowptr[d] = beg + ex;            // coalesced
        dinv[d] = rsqrtf((float)(v + 1));  // +1 self-loop
    }
    if (b == NB - 1 && t == 0) rowptr[N] = E;
    __syncthreads();
    for (int i = beg + t; i < end; i += 256) {
        unsigned r = binned[i];
        int loc = atomicAdd(&lcur[r & 255u], 1);
        col[beg + loc] = (int)(r >> BSH);   // scatter inside this bucket's segment
    }
}

// ---------------- g0 = x @ W : 64-row tile, W from global (L1-resident) ----------------
// Slice-major epilogue: feature j lives in slice j/16 at offset j%16.
// g0t[slice][n] = g0 (teleport, unscaled); g0h[slice][n] = dinv[n]*g0 (state).

__global__ void __launch_bounds__(256) gemm_k(const float* __restrict__ x,
                                              const float* __restrict__ W,
                                              const float* __restrict__ dinv,
                                              __half2* __restrict__ g0t,
                                              __half2* __restrict__ g0h, int N) {
    __shared__ float xs[64 * 133];        // ~34 KB -> 4 blocks/CU
    int t = threadIdx.x;
    int n0 = blockIdx.x * 64;
    for (int f = t; f < 64 * 32; f += 256) {
        int r = f >> 5, c4 = f & 31;
        int n = n0 + r;
        float4 v = (n < N) ? ((const float4*)x)[(size_t)n * 32 + c4]
                           : make_float4(0.f, 0.f, 0.f, 0.f);
        float* dp = &xs[r * 133 + c4 * 4];
        dp[0] = v.x; dp[1] = v.y; dp[2] = v.z; dp[3] = v.w;
    }
    __syncthreads();
    int tr = t & 15, tc = t >> 4;
    int r0 = tc * 4;
    const float4* W4 = (const float4*)W;  // 32 KB total -> L1-resident
    float acc[4][4] = {};
#pragma unroll 8
    for (int k = 0; k < 128; ++k) {
        float4 wv = W4[k * 16 + tr];      // 256 B/k, broadcast across tc, L1 hit
#pragma unroll
        for (int i = 0; i < 4; ++i) {
            float xv = xs[(r0 + i) * 133 + k];
            acc[i][0] += xv * wv.x; acc[i][1] += xv * wv.y;
            acc[i][2] += xv * wv.z; acc[i][3] += xv * wv.w;
        }
    }
    int slice = tr >> 2;                  // j0 = tr*4 -> slice j0/16
    int o = (tr & 3) * 2;                 // half2 offset within the 32-B slice row
#pragma unroll
    for (int i = 0; i < 4; ++i) {
        int n = n0 + r0 + i;
        if (n < N) {
            float dn = dinv[n];
            size_t rb = ((size_t)slice * (N + 1) + n) * 8;
            g0t[rb + o]     = __floats2half2_rn(acc[i][0], acc[i][1]);
            g0t[rb + o + 1] = __floats2half2_rn(acc[i][2], acc[i][3]);
            g0h[rb + o]     = __floats2half2_rn(acc[i][0] * dn, acc[i][1] * dn);
            g0h[rb + o + 1] = __floats2half2_rn(acc[i][2] * dn, acc[i][3] * dn);
        }
    }
}

// ---------------- propagation: 4-slice, XCD-pinned, 4 rows/wave ----------------
// Grid = pairs*8; xcd = bid&7; slice = xcd>>1; seq = (bid>>3)*2 + (xcd&1).
// Block = 4 waves x 4 rows = 16 rows of one slice.
// Wave lanes: r = lane>>4 (row), e = (lane>>1)&7 (edge slot), q = lane&1
// (16-B half of the 32-B slice row). One dwordx4 instr = 32 edge-gathers.

__global__ void __launch_bounds__(256) prop_k(const __half2* __restrict__ gin,
                                              const __half2* __restrict__ g0t,
                                              __half2* __restrict__ gout,
                                              float* __restrict__ outf,
                                              const int* __restrict__ rowptr,
                                              const int* __restrict__ cols,
                                              const float* __restrict__ dinv,
                                              const float* __restrict__ bias,
                                              int N, int nseq, int final_step) {
    int bid = blockIdx.x;
    int xcd = bid & 7;
    int slice = xcd >> 1;
    int seq = (bid >> 3) * 2 + (xcd & 1);
    if (seq >= nseq) return;

    int lane = threadIdx.x & 63;
    int wid  = threadIdx.x >> 6;
    int r = lane >> 4;          // row within wave
    int e = (lane >> 1) & 7;    // edge slot
    int q = lane & 1;           // 16-B half
    int qo = q << 4;

    int gw  = seq * 16 + wid * 4 + r;
    int gcl = (gw < N) ? gw : N - 1;

    size_t srow = (size_t)slice * (N + 1);
    const char* gb = (const char*)gin + srow * 32;   // slice base (SGPR)

    int beg = __builtin_nontemporal_load(rowptr + gcl);
    int nxt = __builtin_nontemporal_load(rowptr + gcl + 1);
    int deg = (gw < N) ? (nxt - beg) : 0;
    float di = dinv[gcl];

    // hoisted self + teleport 16-B segments (overlap with gather latency)
    U16 gi;  gi.u  = *(const uint4*)(gb + (size_t)gcl * 32 + qo);
    U16 g0v; g0v.u = *(const uint4*)((const char*)g0t + (srow + gcl) * 32 + qo);

    // wave max degree (deg uniform within each 16-lane row group)
    int md = deg;
    md = max(md, __shfl_xor(md, 16, 64));
    md = max(md, __shfl_xor(md, 32, 64));

    const h2_t SEL_LO = {(_Float16)1.f, (_Float16)0.f};
    const h2_t SEL_HI = {(_Float16)0.f, (_Float16)1.f};
    float a[8] = {};   // this lane's 8 feature accumulators (its q-half)

#pragma unroll 2
    for (int base = 0; base < md; base += 8) {
        int eg = base + e;
        int idx = beg + ((eg < deg) ? eg : 0);
        int c = __builtin_nontemporal_load(cols + idx);  // per-lane direct col
        if (eg >= deg) c = N;                            // dummy zero row (L1-hot)
        U16 v;
        v.u = *(const uint4*)(gb + (((unsigned)c << 5) | (unsigned)qo));
#pragma unroll
        for (int u = 0; u < 4; ++u) {
            a[2 * u]     = __builtin_amdgcn_fdot2(v.h[u], SEL_LO, a[2 * u],     false);
            a[2 * u + 1] = __builtin_amdgcn_fdot2(v.h[u], SEL_HI, a[2 * u + 1], false);
        }
    }

    // reduce across the 8 edge slots (lane bits 1..3; row & q preserved)
#pragma unroll
    for (int off = 2; off <= 8; off <<= 1) {
#pragma unroll
        for (int u = 0; u < 8; ++u) a[u] += __shfl_xor(a[u], off, 64);
    }

    if ((lane & 14) == 0 && gw < N) {   // lanes r*16+q: own row gw, features [8q,8q+8) of slice
        float rr[8];
#pragma unroll
        for (int u = 0; u < 4; ++u) {
            float2 gf = __half22float2(*(__half2*)&gi.h[u]);
            float2 g0 = __half22float2(*(__half2*)&g0v.h[u]);
            rr[2 * u]     = 0.9f * di * (a[2 * u]     + gf.x) + 0.1f * g0.x;
            rr[2 * u + 1] = 0.9f * di * (a[2 * u + 1] + gf.y) + 0.1f * g0.y;
        }
        if (final_step) {
            float4 b0 = ((const float4*)bias)[slice * 4 + q * 2];
            float4 b1 = ((const float4*)bias)[slice * 4 + q * 2 + 1];
            float4* op = (float4*)(outf + (size_t)gw * 64 + slice * 16 + q * 8);
            op[0] = make_float4(rr[0] + b0.x, rr[1] + b0.y, rr[2] + b0.z, rr[3] + b0.w);
            op[1] = make_float4(rr[4] + b1.x, rr[5] + b1.y, rr[6] + b1.z, rr[7] + b1.w);
        } else {
            U16 o;
#pragma unroll
            for (int u = 0; u < 4; ++u) {
                __half2 h = __floats2half2_rn(di * rr[2 * u], di * rr[2 * u + 1]);
                o.h[u] = *(h2_t*)&h;
            }
            *(uint4*)((char*)gout + (srow + gw) * 32 + qo) = o.u;
        }
    }
}

// ---------------- launch ----------------

extern "C" void kernel_launch(void* const* d_in, const int* in_sizes, int n_in,
                              void* d_out, int out_size, void* d_ws, size_t ws_size,
                              hipStream_t stream) {
    const float* x  = (const float*)d_in[0];
    const int*   ei = (const int*)d_in[1];
    const float* W  = (const float*)d_in[2];
    const float* b  = (const float*)d_in[3];
    float* out = (float*)d_out;

    const int N = in_sizes[0] / 128;
    const int E = in_sizes[1] / 2;
    const int* src = ei;
    const int* dst = ei + E;
    const int NB = (N + 255) >> BSH;     // buckets of 256 dsts

    char* w = (char*)d_ws;
    size_t off = 0;
    auto alloc = [&](size_t bytes) -> void* {
        void* p = w + off;
        off += (bytes + 255) & ~(size_t)255;
        return p;
    };
    // slice-major fp16 state: NSL slices x (N+1) rows x 32 B
    const size_t fp16buf = (size_t)NSL * (N + 1) * 32;
    __half2*  g0h    = (__half2*) alloc(fp16buf);   // dinv-scaled initial state
    __half2*  bufA   = (__half2*) alloc(fp16buf);
    __half2*  bufB   = (__half2*) alloc(fp16buf);
    __half2*  g0t    = (__half2*) alloc(fp16buf);   // teleport term (unscaled)
    int*      cols   = (int*)     alloc((size_t)E * 4);
    unsigned* binned = (unsigned*)alloc((size_t)E * 4);
    int*      rowptr = (int*)     alloc((size_t)(N + 1) * 4);
    int*      bktcnt = (int*)     alloc((size_t)NB * 4);
    int*      bktbase= (int*)     alloc((size_t)(NB + 1) * 4);
    int*      bktcur = (int*)     alloc((size_t)NB * 16 * 4);    // 64B-padded
    float*    dinvv  = (float*)   alloc((size_t)N * 4);

    const int nblkB = (E + 4095) / 4096;

    // ---- build dst-CSR: bucket hist -> scan -> binsort -> per-bucket fill ----
    zero_i32<<<(NB + 255) / 256, 256, 0, stream>>>(bktcnt, NB);
    bucket_hist_k<<<nblkB, 256, 0, stream>>>(dst, E, bktcnt);
    zero_dummy<<<1, 96, 0, stream>>>(g0h, bufA, bufB, N);
    bucket_scan_k<<<1, 256, 0, stream>>>(bktcnt, NB, E, bktbase, bktcur);
    binsort_k<<<nblkB, 256, 0, stream>>>(src, dst, E, bktcur, binned);
    fill2_k<<<NB, 256, 0, stream>>>(binned, bktbase, N, E, NB, rowptr, dinvv, cols);

    // g0 = x @ W (propagation commutes with the linear head)
    gemm_k<<<(N + 63) / 64, 256, 0, stream>>>(x, W, dinvv, g0t, g0h, N);

    // K = 10 APPNP steps, fp16 ping-pong; last step writes fp32 d_out (+bias)
    const int nseq  = (N + 15) / 16;          // 16 rows per block (4 waves x 4 rows)
    const int pairs = (nseq + 1) / 2;
    const int grid  = pairs * 8;              // 8 XCD lanes (4 slices x 2)
    const __half2* gin = g0h;
    __half2* pp[2] = {bufA, bufB};
    for (int k = 0; k < 10; ++k) {
        const bool fin = (k == 9);
        __half2* gout = pp[k & 1];
        prop_k<<<grid, 256, 0, stream>>>(gin, g0t, gout, out, rowptr, cols,
                                         dinvv, b, N, nseq, fin ? 1 : 0);
        gin = gout;
    }
}

// Round 5
// 1122.211 us; speedup vs baseline: 1.2937x; 1.1605x over previous
//
#include <hip/hip_runtime.h>
#include <hip/hip_fp16.h>
#include <math.h>

// dst-CSR built with ZERO N-wide passes: bucket_hist/scan/binsort/fill2.
// + degree-order counting sort (deg_hist/deg_scan/deg_scatter): waves get 4
//   equal-degree rows -> minimal md-padding, wave-coherent masks.
// gemm_k: no W staging (L1-resident), 64-row x tile; slice-major fp16 epilogue.
// prop_k (r5): feature-sliced (4 x 32 B, per-slice 3.2 MB -> L2-resident via
//   blockIdx&7 XCD pinning; FETCH floor proven r3/r4) with latency fixes:
//     - cols loads CACHED (r4's nontemporal put ~900-cyc HBM latency on the
//       critical path -> 30% VALU, latency-bound)
//     - cols software-pipelined: next iter's col pair prefetched during
//       current iter's gathers+fdot2
//     - 16 edges/row/iter = 2 independent gather chains; unroll 2 -> ~4
//       gathers in flight per wave
//     - processing order = degree-sorted (CSR untouched -> bitwise-identical)

#define BSH 8        // 256 dsts per bucket (CSR build)
#define NSL 4        // feature slices; per-slice row = 16 fp16 = 32 B

typedef _Float16 h2_t __attribute__((ext_vector_type(2)));
union U16 { uint4 u; h2_t h[4]; };

// ---------------- small utils ----------------

__global__ void zero_i32(int* __restrict__ p, int n) {
    int i = blockIdx.x * blockDim.x + threadIdx.x;
    if (i < n) p[i] = 0;
}

__global__ void fill_i32(int* __restrict__ p, int n, int v) {
    int i = blockIdx.x * blockDim.x + threadIdx.x;
    if (i < n) p[i] = v;
}

// zero dummy row N of each slice of the three gather buffers
__global__ void zero_dummy(__half2* __restrict__ b0, __half2* __restrict__ b1,
                           __half2* __restrict__ b2, int N) {
    int t = threadIdx.x;
    if (t >= 96) return;              // 3 buffers x 4 slices x 8 half2
    __half2* b = (t < 32) ? b0 : (t < 64) ? b1 : b2;
    int r = t & 31;
    int s = r >> 3, h = r & 7;
    b[((size_t)s * (N + 1) + N) * 8 + h] = __floats2half2_rn(0.f, 0.f);
}

// ---------------- bucket histogram (LDS-aggregated) ----------------

__global__ void __launch_bounds__(256) bucket_hist_k(const int* __restrict__ dst, int E,
                                                     int* __restrict__ bktcnt) {
    __shared__ int hist[400];
    int t = threadIdx.x;
    for (int i = t; i < 400; i += 256) hist[i] = 0;
    __syncthreads();
    int e0 = blockIdx.x * 4096 + t;
#pragma unroll
    for (int i = 0; i < 16; ++i) {
        int e = e0 + i * 256;
        if (e < E) atomicAdd(&hist[dst[e] >> BSH], 1);
    }
    __syncthreads();
    for (int b = t; b < 400; b += 256) {
        int c = hist[b];
        if (c > 0) atomicAdd(&bktcnt[b], c);
    }
}

// ---------------- 1-block scan of bucket totals -> bases + padded cursors ----------------

__global__ void bucket_scan_k(const int* __restrict__ bktcnt, int nb, int E,
                              int* __restrict__ bktbase, int* __restrict__ bktcur) {
    __shared__ int s[256];
    int t = threadIdx.x;
    int C = (nb + 255) / 256;            // <= 8
    int b0 = t * C;
    int loc[8]; int sum = 0;
    for (int i = 0; i < C; ++i) {
        int v = (b0 + i < nb) ? bktcnt[b0 + i] : 0;
        loc[i] = sum; sum += v;
    }
    s[t] = sum; __syncthreads();
    for (int off = 1; off < 256; off <<= 1) {
        int v = (t >= off) ? s[t - off] : 0;
        __syncthreads();
        s[t] += v;
        __syncthreads();
    }
    int excl = s[t] - sum;
    for (int i = 0; i < C; ++i)
        if (b0 + i < nb) {
            int e0 = excl + loc[i];
            bktbase[b0 + i] = e0;
            bktcur[(b0 + i) * 16] = e0;  // 64B-padded cursor
        }
    if (t == 0) bktbase[nb] = E;
}

// ---------------- bin edges by bucket (dst>>8), contiguous runs ----------------

__global__ void __launch_bounds__(256) binsort_k(const int* __restrict__ src,
                                                 const int* __restrict__ dst, int E,
                                                 int* __restrict__ bktcur,  // padded x16
                                                 unsigned* __restrict__ binned) {
    __shared__ int hist[400], gbase[400], lcur[400];
    int t = threadIdx.x;
    for (int i = t; i < 400; i += 256) { hist[i] = 0; lcur[i] = 0; }
    __syncthreads();

    int e0 = blockIdx.x * 4096 + t;
    unsigned rec[16]; int bk[16];
#pragma unroll
    for (int i = 0; i < 16; ++i) {
        int e = e0 + i * 256;
        if (e < E) {
            int s = src[e], d = dst[e];
            bk[i]  = d >> BSH;
            rec[i] = ((unsigned)s << BSH) | (unsigned)(d & 255);
            atomicAdd(&hist[bk[i]], 1);
        } else bk[i] = -1;
    }
    __syncthreads();
    for (int b = t; b < 400; b += 256) {
        int c = hist[b];
        if (c > 0) gbase[b] = atomicAdd(&bktcur[b * 16], c);
    }
    __syncthreads();
#pragma unroll
    for (int i = 0; i < 16; ++i) {
        if (bk[i] >= 0) {
            int loc = atomicAdd(&lcur[bk[i]], 1);
            binned[gbase[bk[i]] + loc] = rec[i];
        }
    }
}

// ---------------- per-bucket: degrees + rowptr + dinv + col scatter ----------------

__global__ void __launch_bounds__(256) fill2_k(const unsigned* __restrict__ binned,
                                               const int* __restrict__ bktbase,
                                               int N, int E, int NB,
                                               int* __restrict__ rowptr,
                                               float* __restrict__ dinv,
                                               int* __restrict__ col) {
    __shared__ int cnt[256], excl[256], lcur[256];
    int b = blockIdx.x, t = threadIdx.x;
    int beg = bktbase[b], end = bktbase[b + 1];
    cnt[t] = 0;
    __syncthreads();
    for (int i = beg + t; i < end; i += 256)
        atomicAdd(&cnt[binned[i] & 255u], 1);
    __syncthreads();
    int v = cnt[t];
    excl[t] = v;
    __syncthreads();
    for (int off = 1; off < 256; off <<= 1) {
        int u = (t >= off) ? excl[t - off] : 0;
        __syncthreads();
        excl[t] += u;
        __syncthreads();
    }
    int ex = excl[t] - v;                // exclusive prefix within bucket
    lcur[t] = ex;
    int d = (b << BSH) + t;
    if (d < N) {
        rowptr[d] = beg + ex;            // coalesced
        dinv[d] = rsqrtf((float)(v + 1));  // +1 self-loop
    }
    if (b == NB - 1 && t == 0) rowptr[N] = E;
    __syncthreads();
    for (int i = beg + t; i < end; i += 256) {
        unsigned r = binned[i];
        int loc = atomicAdd(&lcur[r & 255u], 1);
        col[beg + loc] = (int)(r >> BSH);   // scatter inside this bucket's segment
    }
}

// ---------------- degree-order counting sort (bins = min(deg,255)) ----------------

__global__ void __launch_bounds__(256) deg_hist_k(const int* __restrict__ rowptr, int N,
                                                  int* __restrict__ dhist) {
    __shared__ int h[256];
    int t = threadIdx.x;
    h[t] = 0;
    __syncthreads();
    int i = blockIdx.x * 256 + t;
    if (i < N) {
        int d = rowptr[i + 1] - rowptr[i];
        atomicAdd(&h[d < 255 ? d : 255], 1);
    }
    __syncthreads();
    if (h[t]) atomicAdd(&dhist[t], h[t]);
}

__global__ void deg_scan_k(const int* __restrict__ dhist, int* __restrict__ dcur) {
    __shared__ int s[256];
    int t = threadIdx.x;
    int v = dhist[t];
    s[t] = v; __syncthreads();
    for (int off = 1; off < 256; off <<= 1) {
        int u = (t >= off) ? s[t - off] : 0;
        __syncthreads();
        s[t] += u;
        __syncthreads();
    }
    dcur[t] = s[t] - v;                  // exclusive
}

__global__ void __launch_bounds__(256) deg_scatter_k(const int* __restrict__ rowptr, int N,
                                                     int* __restrict__ dcur,
                                                     int* __restrict__ order) {
    __shared__ int h[256], base[256], lc[256];
    int t = threadIdx.x;
    h[t] = 0; lc[t] = 0;
    __syncthreads();
    int i = blockIdx.x * 256 + t;
    int bin = -1;
    if (i < N) {
        int d = rowptr[i + 1] - rowptr[i];
        bin = d < 255 ? d : 255;
        atomicAdd(&h[bin], 1);
    }
    __syncthreads();
    if (h[t]) base[t] = atomicAdd(&dcur[t], h[t]);
    __syncthreads();
    if (i < N) {
        int l = atomicAdd(&lc[bin], 1);
        order[base[bin] + l] = i;
    }
}

// ---------------- g0 = x @ W : 64-row tile, W from global (L1-resident) ----------------
// Slice-major epilogue: feature j lives in slice j/16 at offset j%16.
// g0t[slice][n] = g0 (teleport, unscaled); g0h[slice][n] = dinv[n]*g0 (state).

__global__ void __launch_bounds__(256) gemm_k(const float* __restrict__ x,
                                              const float* __restrict__ W,
                                              const float* __restrict__ dinv,
                                              __half2* __restrict__ g0t,
                                              __half2* __restrict__ g0h, int N) {
    __shared__ float xs[64 * 133];        // ~34 KB -> 4 blocks/CU
    int t = threadIdx.x;
    int n0 = blockIdx.x * 64;
    for (int f = t; f < 64 * 32; f += 256) {
        int r = f >> 5, c4 = f & 31;
        int n = n0 + r;
        float4 v = (n < N) ? ((const float4*)x)[(size_t)n * 32 + c4]
                           : make_float4(0.f, 0.f, 0.f, 0.f);
        float* dp = &xs[r * 133 + c4 * 4];
        dp[0] = v.x; dp[1] = v.y; dp[2] = v.z; dp[3] = v.w;
    }
    __syncthreads();
    int tr = t & 15, tc = t >> 4;
    int r0 = tc * 4;
    const float4* W4 = (const float4*)W;  // 32 KB total -> L1-resident
    float acc[4][4] = {};
#pragma unroll 8
    for (int k = 0; k < 128; ++k) {
        float4 wv = W4[k * 16 + tr];      // 256 B/k, broadcast across tc, L1 hit
#pragma unroll
        for (int i = 0; i < 4; ++i) {
            float xv = xs[(r0 + i) * 133 + k];
            acc[i][0] += xv * wv.x; acc[i][1] += xv * wv.y;
            acc[i][2] += xv * wv.z; acc[i][3] += xv * wv.w;
        }
    }
    int slice = tr >> 2;                  // j0 = tr*4 -> slice j0/16
    int o = (tr & 3) * 2;                 // half2 offset within the 32-B slice row
#pragma unroll
    for (int i = 0; i < 4; ++i) {
        int n = n0 + r0 + i;
        if (n < N) {
            float dn = dinv[n];
            size_t rb = ((size_t)slice * (N + 1) + n) * 8;
            g0t[rb + o]     = __floats2half2_rn(acc[i][0], acc[i][1]);
            g0t[rb + o + 1] = __floats2half2_rn(acc[i][2], acc[i][3]);
            g0h[rb + o]     = __floats2half2_rn(acc[i][0] * dn, acc[i][1] * dn);
            g0h[rb + o + 1] = __floats2half2_rn(acc[i][2] * dn, acc[i][3] * dn);
        }
    }
}

// ---------------- propagation: 4-slice, XCD-pinned, degree-ordered ----------------
// Grid = pairs*8; xcd = bid&7; slice = xcd>>1; seq = (bid>>3)*2 + (xcd&1).
// Block = 4 waves x 4 rows (degree-sorted order[]) of one slice.
// Wave lanes: r = lane>>4 (row), e = (lane>>1)&7 (edge slot), q = lane&1
// (16-B half of the 32-B slice row). 16 edges/row/iter = 2 gather chains;
// next iter's cols prefetched during current gathers+fdot2.

__global__ void __launch_bounds__(256) prop_k(const __half2* __restrict__ gin,
                                              const __half2* __restrict__ g0t,
                                              __half2* __restrict__ gout,
                                              float* __restrict__ outf,
                                              const int* __restrict__ rowptr,
                                              const int* __restrict__ cols,
                                              const float* __restrict__ dinv,
                                              const float* __restrict__ bias,
                                              const int* __restrict__ order,
                                              int N, int nseq, int final_step) {
    int bid = blockIdx.x;
    int xcd = bid & 7;
    int slice = xcd >> 1;
    int seq = (bid >> 3) * 2 + (xcd & 1);
    if (seq >= nseq) return;

    int lane = threadIdx.x & 63;
    int wid  = threadIdx.x >> 6;
    int r = lane >> 4;          // row within wave
    int e = (lane >> 1) & 7;    // edge slot
    int q = lane & 1;           // 16-B half
    unsigned qo = (unsigned)(q << 4);

    int oi = seq * 16 + wid * 4 + r;
    int gw = order[oi];                 // padded tail holds N
    int gcl = (gw < N) ? gw : 0;        // safe row for scalar reads

    size_t srow = (size_t)slice * (N + 1);
    const char* gb = (const char*)gin + srow * 32;   // slice base (SGPR)

    int beg = rowptr[gcl];
    int deg = (gw < N) ? (rowptr[gcl + 1] - beg) : 0;
    float di = dinv[gcl];

    // hoisted self + teleport 16-B segments (overlap with gather latency)
    U16 gi;  gi.u  = *(const uint4*)(gb + (((unsigned)gcl << 5) | qo));
    U16 g0v; g0v.u = *(const uint4*)((const char*)g0t + (srow + gcl) * 32 + qo);

    // wave max degree (deg uniform within each 16-lane row group)
    int md = deg;
    md = max(md, __shfl_xor(md, 16, 64));
    md = max(md, __shfl_xor(md, 32, 64));

    const h2_t SEL_LO = {(_Float16)1.f, (_Float16)0.f};
    const h2_t SEL_HI = {(_Float16)0.f, (_Float16)1.f};
    float a[8] = {};   // this lane's 8 feature accumulators (its q-half)

    if (md > 0) {
        // prefetch iteration-0 cols
        int c0 = cols[beg + (e < deg ? e : 0)];
        int c1 = cols[beg + (8 + e < deg ? 8 + e : 0)];
#pragma unroll 2
        for (int base = 0; base < md; base += 16) {
            int cc0 = (base + e     < deg) ? c0 : N;   // dummy zero row pad
            int cc1 = (base + 8 + e < deg) ? c1 : N;
            int nb = base + 16;
            if (nb < md) {                             // uniform branch
                c0 = cols[beg + (nb + e     < deg ? nb + e     : 0)];
                c1 = cols[beg + (nb + 8 + e < deg ? nb + 8 + e : 0)];
            }
            U16 v0, v1;
            v0.u = *(const uint4*)(gb + (((unsigned)cc0 << 5) | qo));
            v1.u = *(const uint4*)(gb + (((unsigned)cc1 << 5) | qo));
#pragma unroll
            for (int u = 0; u < 4; ++u) {
                a[2 * u]     = __builtin_amdgcn_fdot2(v0.h[u], SEL_LO, a[2 * u],     false);
                a[2 * u + 1] = __builtin_amdgcn_fdot2(v0.h[u], SEL_HI, a[2 * u + 1], false);
            }
#pragma unroll
            for (int u = 0; u < 4; ++u) {
                a[2 * u]     = __builtin_amdgcn_fdot2(v1.h[u], SEL_LO, a[2 * u],     false);
                a[2 * u + 1] = __builtin_amdgcn_fdot2(v1.h[u], SEL_HI, a[2 * u + 1], false);
            }
        }
    }

    // reduce across the 8 edge slots (lane bits 1..3; row & q preserved)
#pragma unroll
    for (int off = 2; off <= 8; off <<= 1) {
#pragma unroll
        for (int u = 0; u < 8; ++u) a[u] += __shfl_xor(a[u], off, 64);
    }

    if ((lane & 14) == 0 && gw < N) {   // lanes (r,q): row gw, features [8q,8q+8) of slice
        float rr[8];
#pragma unroll
        for (int u = 0; u < 4; ++u) {
            float2 gf = __half22float2(*(__half2*)&gi.h[u]);
            float2 g0 = __half22float2(*(__half2*)&g0v.h[u]);
            rr[2 * u]     = 0.9f * di * (a[2 * u]     + gf.x) + 0.1f * g0.x;
            rr[2 * u + 1] = 0.9f * di * (a[2 * u + 1] + gf.y) + 0.1f * g0.y;
        }
        if (final_step) {
            float4 b0 = ((const float4*)bias)[slice * 4 + q * 2];
            float4 b1 = ((const float4*)bias)[slice * 4 + q * 2 + 1];
            float4* op = (float4*)(outf + (size_t)gw * 64 + slice * 16 + q * 8);
            op[0] = make_float4(rr[0] + b0.x, rr[1] + b0.y, rr[2] + b0.z, rr[3] + b0.w);
            op[1] = make_float4(rr[4] + b1.x, rr[5] + b1.y, rr[6] + b1.z, rr[7] + b1.w);
        } else {
            U16 o;
#pragma unroll
            for (int u = 0; u < 4; ++u) {
                __half2 h = __floats2half2_rn(di * rr[2 * u], di * rr[2 * u + 1]);
                o.h[u] = *(h2_t*)&h;
            }
            *(uint4*)((char*)gout + (srow + gw) * 32 + qo) = o.u;
        }
    }
}

// ---------------- launch ----------------

extern "C" void kernel_launch(void* const* d_in, const int* in_sizes, int n_in,
                              void* d_out, int out_size, void* d_ws, size_t ws_size,
                              hipStream_t stream) {
    const float* x  = (const float*)d_in[0];
    const int*   ei = (const int*)d_in[1];
    const float* W  = (const float*)d_in[2];
    const float* b  = (const float*)d_in[3];
    float* out = (float*)d_out;

    const int N = in_sizes[0] / 128;
    const int E = in_sizes[1] / 2;
    const int* src = ei;
    const int* dst = ei + E;
    const int NB = (N + 255) >> BSH;     // buckets of 256 dsts

    char* w = (char*)d_ws;
    size_t off = 0;
    auto alloc = [&](size_t bytes) -> void* {
        void* p = w + off;
        off += (bytes + 255) & ~(size_t)255;
        return p;
    };
    const int nseq  = (N + 15) / 16;          // 16 rows per block (4 waves x 4)
    // slice-major fp16 state: NSL slices x (N+1) rows x 32 B
    const size_t fp16buf = (size_t)NSL * (N + 1) * 32;
    __half2*  g0h    = (__half2*) alloc(fp16buf);   // dinv-scaled initial state
    __half2*  bufA   = (__half2*) alloc(fp16buf);
    __half2*  bufB   = (__half2*) alloc(fp16buf);
    __half2*  g0t    = (__half2*) alloc(fp16buf);   // teleport term (unscaled)
    int*      cols   = (int*)     alloc((size_t)E * 4);
    unsigned* binned = (unsigned*)alloc((size_t)E * 4);
    int*      rowptr = (int*)     alloc((size_t)(N + 1) * 4);
    int*      bktcnt = (int*)     alloc((size_t)NB * 4);
    int*      bktbase= (int*)     alloc((size_t)(NB + 1) * 4);
    int*      bktcur = (int*)     alloc((size_t)NB * 16 * 4);    // 64B-padded
    float*    dinvv  = (float*)   alloc((size_t)N * 4);
    int*      dhist  = (int*)     alloc(256 * 4);
    int*      dcur   = (int*)     alloc(256 * 4);
    int*      order  = (int*)     alloc((size_t)nseq * 16 * 4);

    const int nblkB = (E + 4095) / 4096;
    const int nblkN = (N + 255) / 256;

    // ---- build dst-CSR: bucket hist -> scan -> binsort -> per-bucket fill ----
    zero_i32<<<(NB + 255) / 256, 256, 0, stream>>>(bktcnt, NB);
    bucket_hist_k<<<nblkB, 256, 0, stream>>>(dst, E, bktcnt);
    zero_dummy<<<1, 96, 0, stream>>>(g0h, bufA, bufB, N);
    bucket_scan_k<<<1, 256, 0, stream>>>(bktcnt, NB, E, bktbase, bktcur);
    binsort_k<<<nblkB, 256, 0, stream>>>(src, dst, E, bktcur, binned);
    fill2_k<<<NB, 256, 0, stream>>>(binned, bktbase, N, E, NB, rowptr, dinvv, cols);

    // ---- degree-order counting sort (one-time) ----
    zero_i32<<<1, 256, 0, stream>>>(dhist, 256);
    fill_i32<<<(nseq * 16 + 255) / 256, 256, 0, stream>>>(order, nseq * 16, N);
    deg_hist_k<<<nblkN, 256, 0, stream>>>(rowptr, N, dhist);
    deg_scan_k<<<1, 256, 0, stream>>>(dhist, dcur);
    deg_scatter_k<<<nblkN, 256, 0, stream>>>(rowptr, N, dcur, order);

    // g0 = x @ W (propagation commutes with the linear head)
    gemm_k<<<(N + 63) / 64, 256, 0, stream>>>(x, W, dinvv, g0t, g0h, N);

    // K = 10 APPNP steps, fp16 ping-pong; last step writes fp32 d_out (+bias)
    const int pairs = (nseq + 1) / 2;
    const int grid  = pairs * 8;              // 8 XCD lanes (4 slices x 2)
    const __half2* gin = g0h;
    __half2* pp[2] = {bufA, bufB};
    for (int k = 0; k < 10; ++k) {
        const bool fin = (k == 9);
        __half2* gout = pp[k & 1];
        prop_k<<<grid, 256, 0, stream>>>(gin, g0t, gout, out, rowptr, cols,
                                         dinvv, b, order, N, nseq, fin ? 1 : 0);
        gin = gout;
    }
}